// Round 2
// baseline (272.501 us; speedup 1.0000x reference)
//
#include <hip/hip_runtime.h>

// LIF repeat-encoder:
//   in  [B=64, C=64, L=512] fp32
//   out [B=64, T=32, L=512, C=64] fp32 (spikes, 0.0 or 1.0)
// Recurrence per element x: v += (x - v)/2 ; s = (v >= 1) ; v = v*(1-s)
//
// R1 analysis: stores were already perfect (contiguous 1 KiB/wave/t), but the
// input reads were lane-stride-8KB scalar loads = 64 cache-line requests per
// load instruction (~2M chip-wide), an L1/L2 request-rate bottleneck.
// Fix: coalesced float4 staging through LDS:
//   - load  : thread (c=tid>>2, q=tid&3) reads float4 in[b, c, l0+q*4..+3]
//             -> 16 full 64B lines per wave-instruction, 16B/lane
//   - LDS   : transpose to lds[l_local][c] (4 KB; 4-way write alias on the
//             tiny staging write, 2-way (free) alias on the b128 readback)
//   - compute: thread (c4=tid&15, ll=tid>>4) reads float4 lds[ll][c4*4]
// Stores: nontemporal (zero reuse; don't churn L2 full of 0xAA poison lines).
// NUMERICS: keep exactly v + (x - v)*0.5f (spike flip at threshold = absmax 1).

constexpr int B = 64;
constexpr int C = 64;
constexpr int L = 512;
constexpr int T = 32;

typedef float vf4 __attribute__((ext_vector_type(4)));

__global__ __launch_bounds__(256) void lif_repeat_kernel(
    const float* __restrict__ in, float* __restrict__ out) {
  __shared__ float lds[16 * 64];  // [l_local][c], 4 KB
  const int blk = blockIdx.x;
  const int tid = threadIdx.x;
  const int b  = blk >> 5;         // 32 blocks per batch
  const int l0 = (blk & 31) * 16;  // 16 l-positions per block

  // ---- coalesced global -> LDS staging (1 float4 load per thread)
  {
    const int c = tid >> 2;  // 0..63
    const int q = tid & 3;   // which float4 of the 16-float l-row
    const vf4 v = *(const vf4*)(in + (size_t)b * (C * L) + (size_t)c * L + l0 + q * 4);
    float* p = lds + c;
    p[(q * 4 + 0) * 64] = v.x;
    p[(q * 4 + 1) * 64] = v.y;
    p[(q * 4 + 2) * 64] = v.z;
    p[(q * 4 + 3) * 64] = v.w;
  }
  __syncthreads();

  // ---- per-thread x fragment from LDS (ds_read_b128, 2-way alias = free)
  const int c4 = tid & 15;   // channel group (4 consecutive c)
  const int ll = tid >> 4;   // 0..15 local l
  const vf4 x = *(const vf4*)(lds + ll * 64 + c4 * 4);

  // ---- output: wave writes contiguous 1 KiB per t
  vf4* op = (vf4*)(out + (size_t)b * (T * L * C) + (size_t)(l0 + ll) * C + c4 * 4);
  constexpr int t_stride4 = (L * C) / 4;  // 8192 vf4 per time step

  float v0 = 0.f, v1 = 0.f, v2 = 0.f, v3 = 0.f;
#pragma unroll
  for (int t = 0; t < T; ++t) {
    v0 += (x.x - v0) * 0.5f;
    v1 += (x.y - v1) * 0.5f;
    v2 += (x.z - v2) * 0.5f;
    v3 += (x.w - v3) * 0.5f;
    vf4 s;
    s.x = (v0 >= 1.0f) ? 1.0f : 0.0f;
    s.y = (v1 >= 1.0f) ? 1.0f : 0.0f;
    s.z = (v2 >= 1.0f) ? 1.0f : 0.0f;
    s.w = (v3 >= 1.0f) ? 1.0f : 0.0f;
    __builtin_nontemporal_store(s, op + (size_t)t * t_stride4);
    v0 = (s.x != 0.0f) ? 0.0f : v0;
    v1 = (s.y != 0.0f) ? 0.0f : v1;
    v2 = (s.z != 0.0f) ? 0.0f : v2;
    v3 = (s.w != 0.0f) ? 0.0f : v3;
  }
}

extern "C" void kernel_launch(void* const* d_in, const int* in_sizes, int n_in,
                              void* d_out, int out_size, void* d_ws, size_t ws_size,
                              hipStream_t stream) {
  const float* in = (const float*)d_in[0];
  float* out = (float*)d_out;
  const int grid = B * 32;  // 2048 blocks; block = (16 l) x (64 c) for one b
  lif_repeat_kernel<<<grid, 256, 0, stream>>>(in, out);
}

// Round 3
// 259.329 us; speedup vs baseline: 1.0508x; 1.0508x over previous
//
#include <hip/hip_runtime.h>

// LIF repeat-encoder:
//   in  [B=64, C=64, L=512] fp32
//   out [B=64, T=32, L=512, C=64] fp32 (spikes, 0.0 or 1.0)
// Recurrence per element x: v += (x - v)/2 ; s = (v >= 1) ; v = v*(1-s)
//
// R2 post-mortem: dur_us ~= fixed ~170us poison-fill + kernel(<169us).
// Kernel effective write BW ~2.8 TB/s vs 6.3 TB/s fill ceiling. Theory:
// write-stream locality — 8192 waves each scattering 1-KiB chunks at 128-KB
// t-stride thrash DRAM rows. Fix: t-OUTER loop over a 64l x 64c register-
// resident tile (16 LIF states/thread): per t a block writes 16 KB contiguous
// (4x R2), 4 stores/thread ILP, block walks a fixed 4 MB window across t.
// Stores: regular (non-NT) — match the fill's L2 write-back path.
// NUMERICS: keep exactly v + (x - v)*0.5f (spike flip at threshold = absmax 1).

constexpr int B = 64;
constexpr int C = 64;
constexpr int L = 512;
constexpr int T = 32;

typedef float vf4 __attribute__((ext_vector_type(4)));

__global__ __launch_bounds__(256) void lif_repeat_kernel(
    const float* __restrict__ in, float* __restrict__ out) {
  __shared__ float lds[64 * 64];   // [l_local][c], 16 KB
  const int tid = threadIdx.x;
  const int b  = blockIdx.x >> 3;          // 8 l-tiles per batch
  const int l0 = (blockIdx.x & 7) * 64;    // 64 l-positions per block

  // ---- coalesced global -> LDS staging (4 float4 loads per thread)
  {
    const int c = tid >> 2;  // 0..63
    const int q = tid & 3;
    const float* ip = in + (size_t)b * (C * L) + (size_t)c * L + l0;
#pragma unroll
    for (int k = 0; k < 4; ++k) {
      const int lo = q * 4 + k * 16;           // l offset, multiple of 4
      const vf4 v = *(const vf4*)(ip + lo);
      lds[(lo + 0) * 64 + c] = v.x;
      lds[(lo + 1) * 64 + c] = v.y;
      lds[(lo + 2) * 64 + c] = v.z;
      lds[(lo + 3) * 64 + c] = v.w;
    }
  }
  __syncthreads();

  // ---- thread owns 16 elements: (l = rr + 16*j, c = c4*4 .. +3), j=0..3
  const int c4 = tid & 15;
  const int rr = tid >> 4;   // 0..15; wave w covers rr in {4w..4w+3}
  float x[4][4], v[4][4];
#pragma unroll
  for (int j = 0; j < 4; ++j) {
    const vf4 xv = *(const vf4*)(lds + (rr + 16 * j) * 64 + c4 * 4);
    x[j][0] = xv.x; x[j][1] = xv.y; x[j][2] = xv.z; x[j][3] = xv.w;
    v[j][0] = v[j][1] = v[j][2] = v[j][3] = 0.f;
  }

  // Per (wave, j): 4 consecutive l-rows x 64 c = 1 KiB contiguous; per t the
  // block's 4 waves x 4 j cover 16 KB contiguous at out[b][t][l0..l0+63][*].
  float* const obase = out + (size_t)b * (T * L * C) + (size_t)l0 * C + c4 * 4;
  constexpr size_t t_stride = (size_t)L * C;  // floats per time step

#pragma unroll 2
  for (int t = 0; t < T; ++t) {
    float* ot = obase + (size_t)t * t_stride;
#pragma unroll
    for (int j = 0; j < 4; ++j) {
      vf4 s;
#pragma unroll
      for (int i = 0; i < 4; ++i) {
        v[j][i] += (x[j][i] - v[j][i]) * 0.5f;
      }
      s.x = (v[j][0] >= 1.0f) ? 1.0f : 0.0f;
      s.y = (v[j][1] >= 1.0f) ? 1.0f : 0.0f;
      s.z = (v[j][2] >= 1.0f) ? 1.0f : 0.0f;
      s.w = (v[j][3] >= 1.0f) ? 1.0f : 0.0f;
      *(vf4*)(ot + (size_t)(rr + 16 * j) * C) = s;
#pragma unroll
      for (int i = 0; i < 4; ++i) {
        v[j][i] = (v[j][i] >= 1.0f) ? 0.0f : v[j][i];
      }
    }
  }
}

extern "C" void kernel_launch(void* const* d_in, const int* in_sizes, int n_in,
                              void* d_out, int out_size, void* d_ws, size_t ws_size,
                              hipStream_t stream) {
  const float* in = (const float*)d_in[0];
  float* out = (float*)d_out;
  const int grid = B * (L / 64);  // 512 blocks
  lif_repeat_kernel<<<grid, 256, 0, stream>>>(in, out);
}